// Round 3
// baseline (1012.131 us; speedup 1.0000x reference)
//
#include <hip/hip_runtime.h>
#include <hip/hip_bf16.h>
#include <math.h>

#define EMB_ATOM 256
#define EMB_EDGE 512
#define K_TOT    1024

typedef __attribute__((ext_vector_type(8))) short bf16x8;
typedef __attribute__((ext_vector_type(4))) float f32x4;
typedef struct { unsigned short x, y, z, w; } us4;

static __device__ __forceinline__ unsigned short f2bf(float f) {
  union { float f; unsigned u; } x; x.f = f;
  unsigned r = x.u + 0x7fffu + ((x.u >> 16) & 1u);   // RTNE
  return (unsigned short)(r >> 16);
}
static __device__ __forceinline__ float bf2f(unsigned short b) {
  union { unsigned u; float f; } x; x.u = ((unsigned)b) << 16; return x.f;
}
static __device__ __forceinline__ us4 f4bf(float4 v) {
  us4 o; o.x = f2bf(v.x); o.y = f2bf(v.y); o.z = f2bf(v.z); o.w = f2bf(v.w); return o;
}
static __device__ __forceinline__ bf16x8 cvt8(float4 a, float4 b) {
  bf16x8 r;
  r[0] = (short)f2bf(a.x); r[1] = (short)f2bf(a.y);
  r[2] = (short)f2bf(a.z); r[3] = (short)f2bf(a.w);
  r[4] = (short)f2bf(b.x); r[5] = (short)f2bf(b.y);
  r[6] = (short)f2bf(b.z); r[7] = (short)f2bf(b.w);
  return r;
}
static __device__ __forceinline__ void gload_lds16(const void* g, void* l) {
  __builtin_amdgcn_global_load_lds(
      (const __attribute__((address_space(1))) unsigned int*)g,
      (__attribute__((address_space(3))) unsigned int*)l, 16, 0, 0);
}
static __device__ __forceinline__ float silu_f(float x) { return x / (1.f + __expf(-x)); }

// ---------------- prep kernels ----------------
__global__ __launch_bounds__(256) void cvt_h_kernel(const float* __restrict__ h,
                                                    unsigned short* __restrict__ hb, int n4) {
  int i = blockIdx.x * 256 + threadIdx.x;
  if (i >= n4) return;
  const float4 v = ((const float4*)h)[i];
  ((us4*)hb)[i] = f4bf(v);
}

// Wt_h: (1024 c, 256 k) bf16, c-major.  c<512: W[k][c]; c>=512: W[256+k][c-512]
__global__ __launch_bounds__(256) void cvt_wh_kernel(const float* __restrict__ W,
                                                     unsigned short* __restrict__ Wt_h) {
  int o = blockIdx.x * 256 + threadIdx.x;    // 1024*256
  int c = o >> 8, k = o & 255;
  float v = (c < 512) ? W[(size_t)k * EMB_EDGE + c]
                      : W[(size_t)(256 + k) * EMB_EDGE + (c - 512)];
  Wt_h[o] = f2bf(v);
}

// Wt_m: (512 c, 512 k) bf16, c-major.  Wt_m[c][k] = W[512+k][c]
__global__ __launch_bounds__(256) void cvt_wm_kernel(const float* __restrict__ W,
                                                     unsigned short* __restrict__ Wt_m) {
  int o = blockIdx.x * 256 + threadIdx.x;    // 512*512
  int c = o >> 9, k = o & 511;
  Wt_m[o] = f2bf(W[(size_t)(512 + k) * EMB_EDGE + c]);
}

// ---------------- H-GEMM: H12 = hb @ [W1|W2]  (N x 1024, bf16) ----------------
__global__ __launch_bounds__(256) void hgemm_kernel(
    const unsigned short* __restrict__ hb,     // (N,256)
    const unsigned short* __restrict__ Wt_h,   // (1024,256) c-major
    unsigned short* __restrict__ H12, int N)
{
  __shared__ unsigned short As[2][128 * 64];
  __shared__ unsigned short Bs[2][128 * 64];
  const int bn = blockIdx.x;       // 0..7
  const int bm = blockIdx.y;
  const int row0 = bm * 128;
  const int tid = threadIdx.x, wave = tid >> 6, lane = tid & 63;
  const int srow = lane >> 3;
  const int schunk = ((lane & 7) ^ srow) * 8;  // pre-swizzled source chunk (elems)

  size_t abase[4]; size_t bbase[4];
#pragma unroll
  for (int i = 0; i < 4; ++i) {
    int r = wave * 32 + i * 8 + srow;
    int e = row0 + r; if (e >= N) e = N - 1;
    abase[i] = (size_t)e * EMB_ATOM;
    bbase[i] = (size_t)(bn * 128 + r) * EMB_ATOM;
  }

  const int wr = wave >> 1, wc = wave & 1, fr = lane & 15, fq = lane >> 4;
  const int fs = fr & 7;

  f32x4 acc[4][4];
#pragma unroll
  for (int m = 0; m < 4; ++m)
#pragma unroll
    for (int n = 0; n < 4; ++n) acc[m][n] = (f32x4)0.f;

#pragma unroll
  for (int i = 0; i < 4; ++i) {
    gload_lds16(hb + abase[i] + schunk,   &As[0][(wave * 32 + i * 8) * 64 + lane * 8]);
    gload_lds16(Wt_h + bbase[i] + schunk, &Bs[0][(wave * 32 + i * 8) * 64 + lane * 8]);
  }
  __syncthreads();

  int cur = 0;
  for (int kt = 0; kt < 4; ++kt) {
    int nxt = cur ^ 1;
    if (kt < 3) {
      int kk = (kt + 1) * 64;
#pragma unroll
      for (int i = 0; i < 4; ++i) {
        gload_lds16(hb + abase[i] + kk + schunk,   &As[nxt][(wave * 32 + i * 8) * 64 + lane * 8]);
        gload_lds16(Wt_h + bbase[i] + kk + schunk, &Bs[nxt][(wave * 32 + i * 8) * 64 + lane * 8]);
      }
    }
#pragma unroll
    for (int ks = 0; ks < 2; ++ks) {
      bf16x8 a[4], b[4];
#pragma unroll
      for (int m = 0; m < 4; ++m)
        a[m] = *(const bf16x8*)(&As[cur][(wr * 64 + m * 16 + fr) * 64 + (((ks * 4 + fq) ^ fs) << 3)]);
#pragma unroll
      for (int n = 0; n < 4; ++n)
        b[n] = *(const bf16x8*)(&Bs[cur][(wc * 64 + n * 16 + fr) * 64 + (((ks * 4 + fq) ^ fs) << 3)]);
#pragma unroll
      for (int m = 0; m < 4; ++m)
#pragma unroll
        for (int n = 0; n < 4; ++n)
          acc[m][n] = __builtin_amdgcn_mfma_f32_16x16x32_bf16(a[m], b[n], acc[m][n], 0, 0, 0);
    }
    __syncthreads();
    cur = nxt;
  }

#pragma unroll
  for (int m = 0; m < 4; ++m) {
    int er0 = row0 + wr * 64 + m * 16 + fq * 4;
#pragma unroll
    for (int n = 0; n < 4; ++n) {
      int col = bn * 128 + wc * 64 + n * 16 + fr;
      f32x4 v = acc[m][n];
#pragma unroll
      for (int j = 0; j < 4; ++j) {
        int e = er0 + j;
        if (e < N) H12[(size_t)e * 1024 + col] = f2bf(v[j]);
      }
    }
  }
}

// ---------------- main GEMM: out = SiLU(m_ij @ W3 + H12[i] + H12[j]) ----------------
// No LDS, no barriers: direct-from-global MFMA fragments.
// BM=64 (4 waves x 16 rows), BN=128 (8 n-frags), BK=64 (2 ks), 8 kt steps.

#define MSTEP(KT, CUR, NXT)                                                         \
  {                                                                                 \
    const int ktn = ((KT) + 1 < 8) ? (KT) + 1 : 7;                                  \
    NXT##0 = *(const float4*)(aptr + ktn * 64);                                     \
    NXT##1 = *(const float4*)(aptr + ktn * 64 + 4);                                 \
    NXT##2 = *(const float4*)(aptr + ktn * 64 + 32);                                \
    NXT##3 = *(const float4*)(aptr + ktn * 64 + 36);                                \
    bf16x8 rb[16];                                                                  \
    _Pragma("unroll")                                                               \
    for (int n = 0; n < 8; ++n) {                                                   \
      rb[n * 2]     = *(const bf16x8*)(bbase + n * 8192 + (KT) * 64);               \
      rb[n * 2 + 1] = *(const bf16x8*)(bbase + n * 8192 + (KT) * 64 + 32);          \
    }                                                                               \
    bf16x8 af0 = cvt8(CUR##0, CUR##1);                                              \
    bf16x8 af1 = cvt8(CUR##2, CUR##3);                                              \
    _Pragma("unroll")                                                               \
    for (int n = 0; n < 8; ++n) {                                                   \
      acc[n] = __builtin_amdgcn_mfma_f32_16x16x32_bf16(af0, rb[n * 2], acc[n], 0, 0, 0);     \
      acc[n] = __builtin_amdgcn_mfma_f32_16x16x32_bf16(af1, rb[n * 2 + 1], acc[n], 0, 0, 0); \
    }                                                                               \
  }

__global__ __launch_bounds__(256) void mgemm_kernel(
    const float* __restrict__ m_ij,
    const int* __restrict__ idx_i,
    const int* __restrict__ idx_j,
    const unsigned short* __restrict__ Wt_m,   // (512,512) c-major
    const unsigned short* __restrict__ H12,    // (N,1024)
    float* __restrict__ out, int E, int nbm)
{
  // XCD-pairing map: the 4 bn-blocks of one bm share id%8 -> same XCD (A-panel L2 reuse)
  int b  = blockIdx.x;
  int bm = (b >> 5) * 8 + (b & 7);
  int bn = (b >> 3) & 3;
  if (bm >= nbm) return;
  const int row0 = bm * 64;
  const int tid = threadIdx.x, wave = tid >> 6, lane = tid & 63;
  const int fr = lane & 15, fq = lane >> 4;

  int arow = row0 + wave * 16 + fr; if (arow >= E) arow = E - 1;
  const float*          aptr  = m_ij + (size_t)arow * EMB_EDGE + fq * 8;
  const unsigned short* bbase = Wt_m + (size_t)(bn * 128 + fr) * 512 + fq * 8;

  f32x4 acc[8];
#pragma unroll
  for (int n = 0; n < 8; ++n) acc[n] = (f32x4)0.f;

  float4 raA0, raA1, raA2, raA3, raB0, raB1, raB2, raB3;
  raA0 = *(const float4*)(aptr);
  raA1 = *(const float4*)(aptr + 4);
  raA2 = *(const float4*)(aptr + 32);
  raA3 = *(const float4*)(aptr + 36);

  for (int kt = 0; kt < 8; kt += 2) {
    MSTEP(kt,     raA, raB)
    MSTEP(kt + 1, raB, raA)
  }

  // epilogue: gather H12 + SiLU + store
#pragma unroll
  for (int j = 0; j < 4; ++j) {
    int e = row0 + wave * 16 + fq * 4 + j;
    if (e < E) {
      const unsigned short* gi = H12 + (size_t)idx_i[e] * 1024 + bn * 128 + fr;
      const unsigned short* gj = H12 + (size_t)idx_j[e] * 1024 + 512 + bn * 128 + fr;
      float* op = out + (size_t)e * EMB_EDGE + bn * 128 + fr;
#pragma unroll
      for (int n = 0; n < 8; ++n) {
        float x = acc[n][j] + bf2f(gi[n * 16]) + bf2f(gj[n * 16]);
        op[n * 16] = silu_f(x);
      }
    }
  }
}

// ---------------- fallback (round-1 fused path, needs only ~27 MB ws) ----------------
__global__ __launch_bounds__(256) void cvt_wt_kernel(const float* __restrict__ W,
                                                     unsigned short* __restrict__ Wt) {
  int o = blockIdx.x * 256 + threadIdx.x;
  int n = o >> 10, k = o & 1023;
  Wt[o] = f2bf(W[(size_t)k * EMB_EDGE + n]);
}

__global__ __launch_bounds__(256) void gemm_gather_kernel(
    const unsigned short* __restrict__ hb,
    const float* __restrict__ m_ij,
    const int* __restrict__ idx_i,
    const int* __restrict__ idx_j,
    const unsigned short* __restrict__ Wt,
    float* __restrict__ out, int E)
{
  __shared__ unsigned short As[128 * 64];
  __shared__ unsigned short Bs[128 * 64];
  const int bn = blockIdx.x, bm = blockIdx.y;
  const int tid = threadIdx.x, wave = tid >> 6, lane = tid & 63;
  const int row0 = bm * 128;
  const int srow = lane >> 3, scol = (lane & 7) * 8;
  int arow[4], aii[4], ajj[4];
#pragma unroll
  for (int i = 0; i < 4; ++i) {
    int r = wave * 32 + i * 8 + srow;
    int e = row0 + r; if (e >= E) e = E - 1;
    arow[i] = r; aii[i] = idx_i[e]; ajj[i] = idx_j[e];
  }
  const int wr = wave >> 1, wc = wave & 1, fr = lane & 15, fq = lane >> 4;
  f32x4 acc[4][4];
#pragma unroll
  for (int m = 0; m < 4; ++m)
#pragma unroll
    for (int n = 0; n < 4; ++n) acc[m][n] = (f32x4)0.f;
  for (int kt = 0; kt < 16; ++kt) {
    __syncthreads();
#pragma unroll
    for (int i = 0; i < 4; ++i) {
      int nl = wave * 32 + i * 8 + srow;
      gload_lds16(Wt + (size_t)(bn * 128 + nl) * K_TOT + kt * 64 + scol, &Bs[nl * 64 + scol]);
    }
    if (kt < 8) {
      const int kh = (kt & 3) * 64;
#pragma unroll
      for (int i = 0; i < 4; ++i) {
        int idx = (kt < 4) ? aii[i] : ajj[i];
        gload_lds16(hb + (size_t)idx * EMB_ATOM + kh + scol, &As[arow[i] * 64 + scol]);
      }
    } else {
      const int kk = (kt - 8) * 64;
#pragma unroll
      for (int it = 0; it < 8; ++it) {
        int flat = it * 1024 + tid * 4;
        int r = flat >> 6, c = flat & 63;
        int e = row0 + r; if (e >= E) e = E - 1;
        const float4 v = *(const float4*)(m_ij + (size_t)e * EMB_EDGE + kk + c);
        *(us4*)(&As[r * 64 + c]) = f4bf(v);
      }
    }
    __syncthreads();
#pragma unroll
    for (int ks = 0; ks < 2; ++ks) {
      bf16x8 a[4], b[4];
#pragma unroll
      for (int m = 0; m < 4; ++m)
        a[m] = *(const bf16x8*)(&As[(wr * 64 + m * 16 + fr) * 64 + ks * 32 + fq * 8]);
#pragma unroll
      for (int n = 0; n < 4; ++n)
        b[n] = *(const bf16x8*)(&Bs[(wc * 64 + n * 16 + fr) * 64 + ks * 32 + fq * 8]);
#pragma unroll
      for (int m = 0; m < 4; ++m)
#pragma unroll
        for (int n = 0; n < 4; ++n)
          acc[m][n] = __builtin_amdgcn_mfma_f32_16x16x32_bf16(a[m], b[n], acc[m][n], 0, 0, 0);
    }
  }
#pragma unroll
  for (int m = 0; m < 4; ++m) {
    int er0 = row0 + wr * 64 + m * 16 + fq * 4;
#pragma unroll
    for (int n = 0; n < 4; ++n) {
      int col = bn * 128 + wc * 64 + n * 16 + fr;
      f32x4 v = acc[m][n];
#pragma unroll
      for (int j = 0; j < 4; ++j) {
        int e = er0 + j;
        if (e < E) out[(size_t)e * EMB_EDGE + col] = silu_f(v[j]);
      }
    }
  }
}

extern "C" void kernel_launch(void* const* d_in, const int* in_sizes, int n_in,
                              void* d_out, int out_size, void* d_ws, size_t ws_size,
                              hipStream_t stream) {
  const float* h    = (const float*)d_in[0];
  const float* m_ij = (const float*)d_in[1];
  const int*   ii   = (const int*)d_in[2];
  const int*   jj   = (const int*)d_in[3];
  const float* W    = (const float*)d_in[4];
  float* out = (float*)d_out;

  const int hsz = in_sizes[0];
  const int N   = hsz / EMB_ATOM;
  const int E   = in_sizes[2];

  unsigned short* hb   = (unsigned short*)d_ws;              // hsz
  unsigned short* Wt_h = hb + hsz;                           // 1024*256
  unsigned short* Wt_m = Wt_h + 1024 * 256;                  // 512*512
  unsigned short* H12  = Wt_m + 512 * 512;                   // N*1024
  size_t need = ((size_t)hsz + 1024 * 256 + 512 * 512 + (size_t)N * 1024) * 2;

  if (ws_size >= need) {
    cvt_h_kernel<<<(hsz / 4 + 255) / 256, 256, 0, stream>>>(h, hb, hsz / 4);
    cvt_wh_kernel<<<1024, 256, 0, stream>>>(W, Wt_h);
    cvt_wm_kernel<<<1024, 256, 0, stream>>>(W, Wt_m);
    int nbmh = (N + 127) / 128;
    hgemm_kernel<<<dim3(8, nbmh), 256, 0, stream>>>(hb, Wt_h, H12, N);
    int nbm  = (E + 63) / 64;
    int ngrp = (nbm + 7) / 8;
    mgemm_kernel<<<ngrp * 32, 256, 0, stream>>>(m_ij, ii, jj, Wt_m, H12, out, E, nbm);
  } else {
    unsigned short* Wt  = (unsigned short*)d_ws;             // 512*1024
    unsigned short* hbf = Wt + 512 * 1024;                   // hsz
    cvt_wt_kernel<<<(512 * 1024) / 256, 256, 0, stream>>>(W, Wt);
    cvt_h_kernel<<<(hsz / 4 + 255) / 256, 256, 0, stream>>>(h, hbf, hsz / 4);
    dim3 grid(4, (E + 127) / 128);
    gemm_gather_kernel<<<grid, 256, 0, stream>>>(hbf, m_ij, ii, jj, Wt, out, E);
  }
}

// Round 4
// 453.740 us; speedup vs baseline: 2.2306x; 2.2306x over previous
//
#include <hip/hip_runtime.h>
#include <hip/hip_bf16.h>
#include <math.h>

#define EMB_ATOM 256
#define EMB_EDGE 512
#define K_TOT    1024

typedef __attribute__((ext_vector_type(8))) short bf16x8;
typedef __attribute__((ext_vector_type(4))) float f32x4;
typedef struct { unsigned short x, y, z, w; } us4;

static __device__ __forceinline__ unsigned short f2bf(float f) {
  union { float f; unsigned u; } x; x.f = f;
  unsigned r = x.u + 0x7fffu + ((x.u >> 16) & 1u);   // RTNE
  return (unsigned short)(r >> 16);
}
static __device__ __forceinline__ float bf2f(unsigned short b) {
  union { unsigned u; float f; } x; x.u = ((unsigned)b) << 16; return x.f;
}
static __device__ __forceinline__ us4 f4bf(float4 v) {
  us4 o; o.x = f2bf(v.x); o.y = f2bf(v.y); o.z = f2bf(v.z); o.w = f2bf(v.w); return o;
}
// two float4 chunks -> bf16x8 via v_cvt_pk_bf16_f32 (RTNE)
static __device__ __forceinline__ bf16x8 cvt8(float4 a, float4 b) {
  union { bf16x8 v; __hip_bfloat162 h[4]; } u;
  u.h[0] = __float22bfloat162_rn(make_float2(a.x, a.y));
  u.h[1] = __float22bfloat162_rn(make_float2(a.z, a.w));
  u.h[2] = __float22bfloat162_rn(make_float2(b.x, b.y));
  u.h[3] = __float22bfloat162_rn(make_float2(b.z, b.w));
  return u.v;
}
static __device__ __forceinline__ void gload_lds16(const void* g, void* l) {
  __builtin_amdgcn_global_load_lds(
      (const __attribute__((address_space(1))) unsigned int*)g,
      (__attribute__((address_space(3))) unsigned int*)l, 16, 0, 0);
}
static __device__ __forceinline__ float silu_f(float x) { return x / (1.f + __expf(-x)); }

// ---------------- prep kernels ----------------
__global__ __launch_bounds__(256) void cvt_h_kernel(const float* __restrict__ h,
                                                    unsigned short* __restrict__ hb, int n4) {
  int i = blockIdx.x * 256 + threadIdx.x;
  if (i >= n4) return;
  const float4 v = ((const float4*)h)[i];
  ((us4*)hb)[i] = f4bf(v);
}

// Wt_h: (1024 c, 256 k) bf16, c-major.  c<512: W[k][c]; c>=512: W[256+k][c-512]
__global__ __launch_bounds__(256) void cvt_wh_kernel(const float* __restrict__ W,
                                                     unsigned short* __restrict__ Wt_h) {
  int o = blockIdx.x * 256 + threadIdx.x;    // 1024*256
  int c = o >> 8, k = o & 255;
  float v = (c < 512) ? W[(size_t)k * EMB_EDGE + c]
                      : W[(size_t)(256 + k) * EMB_EDGE + (c - 512)];
  Wt_h[o] = f2bf(v);
}

// Wt_m: (512 c, 512 k) bf16, c-major.  Wt_m[c][k] = W[512+k][c]
__global__ __launch_bounds__(256) void cvt_wm_kernel(const float* __restrict__ W,
                                                     unsigned short* __restrict__ Wt_m) {
  int o = blockIdx.x * 256 + threadIdx.x;    // 512*512
  int c = o >> 9, k = o & 511;
  Wt_m[o] = f2bf(W[(size_t)(512 + k) * EMB_EDGE + c]);
}

// ---------------- H-GEMM: H12 = hb @ [W1|W2]  (N x 1024, bf16) ----------------
__global__ __launch_bounds__(256) void hgemm_kernel(
    const unsigned short* __restrict__ hb,     // (N,256)
    const unsigned short* __restrict__ Wt_h,   // (1024,256) c-major
    unsigned short* __restrict__ H12, int N)
{
  __shared__ unsigned short As[2][128 * 64];
  __shared__ unsigned short Bs[2][128 * 64];
  const int bn = blockIdx.x;       // 0..7
  const int bm = blockIdx.y;
  const int row0 = bm * 128;
  const int tid = threadIdx.x, wave = tid >> 6, lane = tid & 63;
  const int srow = lane >> 3;
  const int schunk = ((lane & 7) ^ srow) * 8;  // pre-swizzled source chunk (elems)

  size_t abase[4]; size_t bbase[4];
#pragma unroll
  for (int i = 0; i < 4; ++i) {
    int r = wave * 32 + i * 8 + srow;
    int e = row0 + r; if (e >= N) e = N - 1;
    abase[i] = (size_t)e * EMB_ATOM;
    bbase[i] = (size_t)(bn * 128 + r) * EMB_ATOM;
  }

  const int wr = wave >> 1, wc = wave & 1, fr = lane & 15, fq = lane >> 4;
  const int fs = fr & 7;

  f32x4 acc[4][4];
#pragma unroll
  for (int m = 0; m < 4; ++m)
#pragma unroll
    for (int n = 0; n < 4; ++n) acc[m][n] = (f32x4)0.f;

#pragma unroll
  for (int i = 0; i < 4; ++i) {
    gload_lds16(hb + abase[i] + schunk,   &As[0][(wave * 32 + i * 8) * 64 + lane * 8]);
    gload_lds16(Wt_h + bbase[i] + schunk, &Bs[0][(wave * 32 + i * 8) * 64 + lane * 8]);
  }
  __syncthreads();

  int cur = 0;
  for (int kt = 0; kt < 4; ++kt) {
    int nxt = cur ^ 1;
    if (kt < 3) {
      int kk = (kt + 1) * 64;
#pragma unroll
      for (int i = 0; i < 4; ++i) {
        gload_lds16(hb + abase[i] + kk + schunk,   &As[nxt][(wave * 32 + i * 8) * 64 + lane * 8]);
        gload_lds16(Wt_h + bbase[i] + kk + schunk, &Bs[nxt][(wave * 32 + i * 8) * 64 + lane * 8]);
      }
    }
#pragma unroll
    for (int ks = 0; ks < 2; ++ks) {
      bf16x8 a[4], b[4];
#pragma unroll
      for (int m = 0; m < 4; ++m)
        a[m] = *(const bf16x8*)(&As[cur][(wr * 64 + m * 16 + fr) * 64 + (((ks * 4 + fq) ^ fs) << 3)]);
#pragma unroll
      for (int n = 0; n < 4; ++n)
        b[n] = *(const bf16x8*)(&Bs[cur][(wc * 64 + n * 16 + fr) * 64 + (((ks * 4 + fq) ^ fs) << 3)]);
#pragma unroll
      for (int m = 0; m < 4; ++m)
#pragma unroll
        for (int n = 0; n < 4; ++n)
          acc[m][n] = __builtin_amdgcn_mfma_f32_16x16x32_bf16(a[m], b[n], acc[m][n], 0, 0, 0);
    }
    __syncthreads();
    cur = nxt;
  }

#pragma unroll
  for (int m = 0; m < 4; ++m) {
    int er0 = row0 + wr * 64 + m * 16 + fq * 4;
#pragma unroll
    for (int n = 0; n < 4; ++n) {
      int col = bn * 128 + wc * 64 + n * 16 + fr;
      f32x4 v = acc[m][n];
#pragma unroll
      for (int j = 0; j < 4; ++j) {
        int e = er0 + j;
        if (e < N) H12[(size_t)e * 1024 + col] = f2bf(v[j]);
      }
    }
  }
}

// ---------------- main GEMM: out = SiLU(m_ij @ W3 + H12[i] + H12[j]) ----------------
// m97 structure: single-buffered LDS (A f32 32KB + B bf16 16KB = 48KB, 3 blocks/CU),
// both tiles staged via global_load_lds with pre-swizzled source, 2 barriers / K-tile,
// f32->bf16 cvt at fragment build (v_cvt_pk_bf16_f32).
__global__ __launch_bounds__(256, 3) void mgemm_kernel(
    const float* __restrict__ m_ij,
    const int* __restrict__ idx_i,
    const int* __restrict__ idx_j,
    const unsigned short* __restrict__ Wt_m,   // (512,512) c-major
    const unsigned short* __restrict__ H12,    // (N,1024)
    float* __restrict__ out, int E, int nbm)
{
  __shared__ __align__(16) float          As[128 * 64];   // 32KB, 16B chunks XOR row&15
  __shared__ __align__(16) unsigned short Bs[128 * 64];   // 16KB, 16B chunks XOR row&7

  // XCD-pairing map: the 4 bn-blocks of one bm share id%8 -> same XCD (A-panel L2 reuse)
  int b  = blockIdx.x;
  int bm = (b >> 5) * 8 + (b & 7);
  int bn = (b >> 3) & 3;
  if (bm >= nbm) return;
  const int row0 = bm * 128;
  const int tid = threadIdx.x, wave = tid >> 6, lane = tid & 63;
  const int fr = lane & 15, fq = lane >> 4;
  const int wr = wave >> 1, wc = wave & 1;

  // A staging: 8 glds/wave, each 1KB = 4 rows x 256B. Source pre-swizzled.
  const float* asrc[8];
#pragma unroll
  for (int i = 0; i < 8; ++i) {
    int r = wave * 32 + i * 4 + (lane >> 4);
    int e = row0 + r; if (e >= E) e = E - 1;
    int sc = (lane & 15) ^ (r & 15);
    asrc[i] = m_ij + (size_t)e * EMB_EDGE + sc * 4;
  }
  // B staging: 4 glds/wave, each 1KB = 8 rows x 128B.
  const unsigned short* bsrc[4];
#pragma unroll
  for (int i = 0; i < 4; ++i) {
    int r = wave * 32 + i * 8 + (lane >> 3);
    int sc = (lane & 7) ^ (r & 7);
    bsrc[i] = Wt_m + (size_t)(bn * 128 + r) * 512 + sc * 8;
  }

  f32x4 acc[4][4];
#pragma unroll
  for (int m = 0; m < 4; ++m)
#pragma unroll
    for (int n = 0; n < 4; ++n) acc[m][n] = (f32x4)0.f;

  for (int kt = 0; kt < 8; ++kt) {
    const int kk = kt * 64;
#pragma unroll
    for (int i = 0; i < 8; ++i)
      gload_lds16(asrc[i] + kk, &As[(wave * 32 + i * 4) * 64]);
#pragma unroll
    for (int i = 0; i < 4; ++i)
      gload_lds16(bsrc[i] + kk, &Bs[(wave * 32 + i * 8) * 64]);
    __syncthreads();   // drains vmcnt -> tiles ready

#pragma unroll
    for (int ks = 0; ks < 2; ++ks) {
      bf16x8 bfr[4];
#pragma unroll
      for (int n = 0; n < 4; ++n)
        bfr[n] = *(const bf16x8*)(&Bs[(wc * 64 + n * 16 + fr) * 64 + (((ks * 4 + fq) ^ (fr & 7)) << 3)]);
#pragma unroll
      for (int m = 0; m < 4; ++m) {
        const int row = wr * 64 + m * 16 + fr;
        const int L0  = ks * 8 + fq * 2;
        float4 c0 = *(const float4*)(&As[row * 64 + ((L0 ^ fr) << 2)]);
        float4 c1 = *(const float4*)(&As[row * 64 + (((L0 + 1) ^ fr) << 2)]);
        bf16x8 afr = cvt8(c0, c1);
#pragma unroll
        for (int n = 0; n < 4; ++n)
          acc[m][n] = __builtin_amdgcn_mfma_f32_16x16x32_bf16(afr, bfr[n], acc[m][n], 0, 0, 0);
      }
    }
    __syncthreads();   // reads done before restaging
  }

  // epilogue: gather H12 + SiLU + store
#pragma unroll
  for (int m = 0; m < 4; ++m) {
#pragma unroll
    for (int j = 0; j < 4; ++j) {
      int e = row0 + wr * 64 + m * 16 + fq * 4 + j;
      if (e < E) {
        size_t gi = (size_t)idx_i[e] * 1024;
        size_t gj = (size_t)idx_j[e] * 1024 + 512;
#pragma unroll
        for (int n = 0; n < 4; ++n) {
          int col = bn * 128 + wc * 64 + n * 16 + fr;
          float x = acc[m][n][j] + bf2f(H12[gi + col]) + bf2f(H12[gj + col]);
          out[(size_t)e * EMB_EDGE + col] = silu_f(x);
        }
      }
    }
  }
}

// ---------------- fallback (round-1 fused path, needs only ~27 MB ws) ----------------
__global__ __launch_bounds__(256) void cvt_wt_kernel(const float* __restrict__ W,
                                                     unsigned short* __restrict__ Wt) {
  int o = blockIdx.x * 256 + threadIdx.x;
  int n = o >> 10, k = o & 1023;
  Wt[o] = f2bf(W[(size_t)k * EMB_EDGE + n]);
}

__global__ __launch_bounds__(256) void gemm_gather_kernel(
    const unsigned short* __restrict__ hb,
    const float* __restrict__ m_ij,
    const int* __restrict__ idx_i,
    const int* __restrict__ idx_j,
    const unsigned short* __restrict__ Wt,
    float* __restrict__ out, int E)
{
  __shared__ unsigned short As[128 * 64];
  __shared__ unsigned short Bs[128 * 64];
  const int bn = blockIdx.x, bm = blockIdx.y;
  const int tid = threadIdx.x, wave = tid >> 6, lane = tid & 63;
  const int row0 = bm * 128;
  const int srow = lane >> 3, scol = (lane & 7) * 8;
  int arow[4], aii[4], ajj[4];
#pragma unroll
  for (int i = 0; i < 4; ++i) {
    int r = wave * 32 + i * 8 + srow;
    int e = row0 + r; if (e >= E) e = E - 1;
    arow[i] = r; aii[i] = idx_i[e]; ajj[i] = idx_j[e];
  }
  const int wr = wave >> 1, wc = wave & 1, fr = lane & 15, fq = lane >> 4;
  f32x4 acc[4][4];
#pragma unroll
  for (int m = 0; m < 4; ++m)
#pragma unroll
    for (int n = 0; n < 4; ++n) acc[m][n] = (f32x4)0.f;
  for (int kt = 0; kt < 16; ++kt) {
    __syncthreads();
#pragma unroll
    for (int i = 0; i < 4; ++i) {
      int nl = wave * 32 + i * 8 + srow;
      gload_lds16(Wt + (size_t)(bn * 128 + nl) * K_TOT + kt * 64 + scol, &Bs[nl * 64 + scol]);
    }
    if (kt < 8) {
      const int kh = (kt & 3) * 64;
#pragma unroll
      for (int i = 0; i < 4; ++i) {
        int idx = (kt < 4) ? aii[i] : ajj[i];
        gload_lds16(hb + (size_t)idx * EMB_ATOM + kh + scol, &As[arow[i] * 64 + scol]);
      }
    } else {
      const int kk = (kt - 8) * 64;
#pragma unroll
      for (int it = 0; it < 8; ++it) {
        int flat = it * 1024 + tid * 4;
        int r = flat >> 6, c = flat & 63;
        int e = row0 + r; if (e >= E) e = E - 1;
        const float4 v = *(const float4*)(m_ij + (size_t)e * EMB_EDGE + kk + c);
        *(us4*)(&As[r * 64 + c]) = f4bf(v);
      }
    }
    __syncthreads();
#pragma unroll
    for (int ks = 0; ks < 2; ++ks) {
      bf16x8 a[4], b[4];
#pragma unroll
      for (int m = 0; m < 4; ++m)
        a[m] = *(const bf16x8*)(&As[(wr * 64 + m * 16 + fr) * 64 + ks * 32 + fq * 8]);
#pragma unroll
      for (int n = 0; n < 4; ++n)
        b[n] = *(const bf16x8*)(&Bs[(wc * 64 + n * 16 + fr) * 64 + ks * 32 + fq * 8]);
#pragma unroll
      for (int m = 0; m < 4; ++m)
#pragma unroll
        for (int n = 0; n < 4; ++n)
          acc[m][n] = __builtin_amdgcn_mfma_f32_16x16x32_bf16(a[m], b[n], acc[m][n], 0, 0, 0);
    }
  }
#pragma unroll
  for (int m = 0; m < 4; ++m) {
    int er0 = row0 + wr * 64 + m * 16 + fq * 4;
#pragma unroll
    for (int n = 0; n < 4; ++n) {
      int col = bn * 128 + wc * 64 + n * 16 + fr;
      f32x4 v = acc[m][n];
#pragma unroll
      for (int j = 0; j < 4; ++j) {
        int e = er0 + j;
        if (e < E) out[(size_t)e * EMB_EDGE + col] = silu_f(v[j]);
      }
    }
  }
}

extern "C" void kernel_launch(void* const* d_in, const int* in_sizes, int n_in,
                              void* d_out, int out_size, void* d_ws, size_t ws_size,
                              hipStream_t stream) {
  const float* h    = (const float*)d_in[0];
  const float* m_ij = (const float*)d_in[1];
  const int*   ii   = (const int*)d_in[2];
  const int*   jj   = (const int*)d_in[3];
  const float* W    = (const float*)d_in[4];
  float* out = (float*)d_out;

  const int hsz = in_sizes[0];
  const int N   = hsz / EMB_ATOM;
  const int E   = in_sizes[2];

  unsigned short* hb   = (unsigned short*)d_ws;              // hsz
  unsigned short* Wt_h = hb + hsz;                           // 1024*256
  unsigned short* Wt_m = Wt_h + 1024 * 256;                  // 512*512
  unsigned short* H12  = Wt_m + 512 * 512;                   // N*1024
  size_t need = ((size_t)hsz + 1024 * 256 + 512 * 512 + (size_t)N * 1024) * 2;

  if (ws_size >= need) {
    cvt_h_kernel<<<(hsz / 4 + 255) / 256, 256, 0, stream>>>(h, hb, hsz / 4);
    cvt_wh_kernel<<<1024, 256, 0, stream>>>(W, Wt_h);
    cvt_wm_kernel<<<1024, 256, 0, stream>>>(W, Wt_m);
    int nbmh = (N + 127) / 128;
    hgemm_kernel<<<dim3(8, nbmh), 256, 0, stream>>>(hb, Wt_h, H12, N);
    int nbm  = (E + 127) / 128;
    int ngrp = (nbm + 7) / 8;
    mgemm_kernel<<<ngrp * 32, 256, 0, stream>>>(m_ij, ii, jj, Wt_m, H12, out, E, nbm);
  } else {
    unsigned short* Wt  = (unsigned short*)d_ws;             // 512*1024
    unsigned short* hbf = Wt + 512 * 1024;                   // hsz
    cvt_wt_kernel<<<(512 * 1024) / 256, 256, 0, stream>>>(W, Wt);
    cvt_h_kernel<<<(hsz / 4 + 255) / 256, 256, 0, stream>>>(h, hbf, hsz / 4);
    dim3 grid(4, (E + 127) / 128);
    gemm_gather_kernel<<<grid, 256, 0, stream>>>(hbf, m_ij, ii, jj, Wt, out, E);
  }
}